// Round 1
// 9862.042 us; speedup vs baseline: 1.1191x; 1.1191x over previous
//
#include <hip/hip_runtime.h>
#include <math.h>

#define BATCH 64
#define HDIM 1024
#define EDIM 1024
#define VOCAB 32000
#define TSTEPS 50
#define G4 4096      // 4*H
#define KCAT 2048    // EDIM + HDIM
#define STARTIDX 1

// ---------------------------------------------------------------------------
// init: xcat[b] = [ embedding[START_INDEX] | hidden[b] ],  c = 0
// ---------------------------------------------------------------------------
__global__ __launch_bounds__(256) void init_kernel(
    const float* __restrict__ hidden, const float* __restrict__ embedding,
    float* __restrict__ xcat, float* __restrict__ c)
{
    int tid = blockIdx.x * 256 + threadIdx.x;   // 0 .. 64*2048-1
    int b = tid >> 11;
    int j = tid & 2047;
    if (j < EDIM) {
        xcat[(size_t)b * KCAT + j] = embedding[(size_t)STARTIDX * EDIM + j];
    } else {
        int k = j - EDIM;
        xcat[(size_t)b * KCAT + j] = hidden[(size_t)b * HDIM + k];
        c[(size_t)b * HDIM + k] = 0.0f;
    }
}

// ---------------------------------------------------------------------------
// C_slice[s] (64 x N) = X[:, kbase:kbase+Ks] @ Wsel^T  (+ bias if non-null)
// Tile: 64 rows x 128 cols, 256 threads, 4x8 per-thread micro-tile, KC=16.
// Software-pipelined: register prefetch of tile k0+1 issued BEFORE compute of
// tile k0 (hides ~500-900cy global latency under 1024cy of FMA issue), LDS
// double-buffered so only ONE barrier per k-iteration.
// Numerically identical to the unpipelined version (same FMA order).
// Deterministic: no atomics; K-slices write separate partial buffers.
// ---------------------------------------------------------------------------
__global__ __launch_bounds__(256) void gemm_xwt(
    const float* __restrict__ X, int ldx,
    const float* __restrict__ W0, const float* __restrict__ W1, int ldw,
    const float* __restrict__ bias,
    float* __restrict__ C, size_t c_slice_stride,
    int N, int Ktotal, int nslices, int coltiles)
{
    __shared__ float Xs[2][16][68];    // [buf][kk][row], pad keeps b128 align
    __shared__ float Ws[2][16][136];   // [buf][kk][col]

    const int tid = threadIdx.x;
    const int bx  = blockIdx.x;
    const int s   = bx / coltiles;
    const int ct  = bx - s * coltiles;
    const int Ks  = Ktotal / nslices;
    const int kbase = s * Ks;
    const float* Xp = X + kbase;
    const float* Wp = (kbase < ldw) ? (W0 + kbase) : (W1 + (kbase - ldw));
    const int colBase = ct * 128;

    const int row0 = (tid >> 4) * 4;      // 0..60
    const int col0 = (tid & 15) * 8;      // 0..120
    const int lr4  = tid >> 2;            // 0..63
    const int lk4  = (tid & 3) << 2;      // 0,4,8,12

    float acc[4][8];
#pragma unroll
    for (int i = 0; i < 4; ++i)
#pragma unroll
        for (int j = 0; j < 8; ++j) acc[i][j] = 0.0f;

    const float* xg  = Xp + (size_t)lr4 * ldx + lk4;
    const float* wg0 = Wp + (size_t)(colBase + lr4) * ldw + lk4;
    const float* wg1 = Wp + (size_t)(colBase + 64 + lr4) * ldw + lk4;

    // ---- prologue: stage tile 0 into buffer 0 ----
    {
        float4 xv = *(const float4*)(xg);
        float4 w0 = *(const float4*)(wg0);
        float4 w1 = *(const float4*)(wg1);
        Xs[0][lk4+0][lr4] = xv.x; Xs[0][lk4+1][lr4] = xv.y;
        Xs[0][lk4+2][lr4] = xv.z; Xs[0][lk4+3][lr4] = xv.w;
        Ws[0][lk4+0][lr4] = w0.x; Ws[0][lk4+1][lr4] = w0.y;
        Ws[0][lk4+2][lr4] = w0.z; Ws[0][lk4+3][lr4] = w0.w;
        Ws[0][lk4+0][64+lr4] = w1.x; Ws[0][lk4+1][64+lr4] = w1.y;
        Ws[0][lk4+2][64+lr4] = w1.z; Ws[0][lk4+3][64+lr4] = w1.w;
    }
    __syncthreads();

    const int niter = Ks >> 4;
    int cur = 0;
#pragma unroll 2
    for (int it = 1; it < niter; ++it) {
        const int k0 = it << 4;
        // prefetch next tile into registers (issued before the FMA block;
        // vmcnt wait lands after ~1024cy of compute -> latency hidden)
        float4 xv = *(const float4*)(xg  + k0);
        float4 w0 = *(const float4*)(wg0 + k0);
        float4 w1 = *(const float4*)(wg1 + k0);

        // compute on current buffer
        {
            const float (*Xc)[68]  = Xs[cur];
            const float (*Wc)[136] = Ws[cur];
#pragma unroll
            for (int kk = 0; kk < 16; ++kk) {
                float4 av = *(const float4*)&Xc[kk][row0];
                float4 b0 = *(const float4*)&Wc[kk][col0];
                float4 b1 = *(const float4*)&Wc[kk][col0 + 4];
                float a[4] = {av.x, av.y, av.z, av.w};
                float bb[8] = {b0.x, b0.y, b0.z, b0.w, b1.x, b1.y, b1.z, b1.w};
#pragma unroll
                for (int i = 0; i < 4; ++i)
#pragma unroll
                    for (int j = 0; j < 8; ++j)
                        acc[i][j] += a[i] * bb[j];
            }
        }

        // stage prefetched tile into the other buffer.
        // Safe with a single barrier: buffer nb was last READ before the
        // previous barrier; all waves in this iteration only read buf cur.
        const int nb = cur ^ 1;
        Xs[nb][lk4+0][lr4] = xv.x; Xs[nb][lk4+1][lr4] = xv.y;
        Xs[nb][lk4+2][lr4] = xv.z; Xs[nb][lk4+3][lr4] = xv.w;
        Ws[nb][lk4+0][lr4] = w0.x; Ws[nb][lk4+1][lr4] = w0.y;
        Ws[nb][lk4+2][lr4] = w0.z; Ws[nb][lk4+3][lr4] = w0.w;
        Ws[nb][lk4+0][64+lr4] = w1.x; Ws[nb][lk4+1][64+lr4] = w1.y;
        Ws[nb][lk4+2][64+lr4] = w1.z; Ws[nb][lk4+3][64+lr4] = w1.w;
        __syncthreads();
        cur = nb;
    }

    // ---- epilogue compute on the last staged tile ----
    {
        const float (*Xc)[68]  = Xs[cur];
        const float (*Wc)[136] = Ws[cur];
#pragma unroll
        for (int kk = 0; kk < 16; ++kk) {
            float4 av = *(const float4*)&Xc[kk][row0];
            float4 b0 = *(const float4*)&Wc[kk][col0];
            float4 b1 = *(const float4*)&Wc[kk][col0 + 4];
            float a[4] = {av.x, av.y, av.z, av.w};
            float bb[8] = {b0.x, b0.y, b0.z, b0.w, b1.x, b1.y, b1.z, b1.w};
#pragma unroll
            for (int i = 0; i < 4; ++i)
#pragma unroll
                for (int j = 0; j < 8; ++j)
                    acc[i][j] += a[i] * bb[j];
        }
    }

    float* Cs = C + (size_t)s * c_slice_stride;
#pragma unroll
    for (int i = 0; i < 4; ++i) {
        const int r = row0 + i;
        float* crow = Cs + (size_t)r * N + colBase + col0;
#pragma unroll
        for (int j = 0; j < 8; ++j) {
            float v = acc[i][j];
            if (bias) v += bias[colBase + col0 + j];
            crow[j] = v;
        }
    }
}

// ---------------------------------------------------------------------------
// cell: gate[b][j] = sum_s gpart[s][b][j] + b_ih[j] + b_hh[j]  (fixed order ->
// deterministic), then LSTM update; h_new written into xcat[:,EDIM:].
// ---------------------------------------------------------------------------
__global__ __launch_bounds__(256) void cell_kernel(
    const float* __restrict__ gpart,   // [8][64*4096]
    const float* __restrict__ b_ih, const float* __restrict__ b_hh,
    float* __restrict__ c, float* __restrict__ xcat)
{
    int tid = blockIdx.x * 256 + threadIdx.x;   // 0..65535
    int b = tid >> 10;
    int k = tid & 1023;
    size_t base = (size_t)b * G4;
    float g[4];
#pragma unroll
    for (int q = 0; q < 4; ++q) {
        int j = k + q * HDIM;
        float v = b_ih[j] + b_hh[j];
#pragma unroll
        for (int sN = 0; sN < 8; ++sN)
            v += gpart[(size_t)sN * ((size_t)BATCH * G4) + base + j];
        g[q] = v;
    }
    float sig_i = 1.0f / (1.0f + expf(-g[0]));
    float sig_f = 1.0f / (1.0f + expf(-g[1]));
    float sig_o = 1.0f / (1.0f + expf(-g[3]));
    float cn = sig_f * c[tid] + sig_i * tanhf(g[2]);
    float hn = sig_o * tanhf(cn);
    c[tid] = cn;
    xcat[(size_t)b * KCAT + EDIM + k] = hn;
}

// ---------------------------------------------------------------------------
// softmax + argmax (first-index tie-break, matches np.argmax) + prob write +
// pred write (as float; out buffer is read as fp32) + gather next embedding.
// One block per batch row.
// ---------------------------------------------------------------------------
__global__ __launch_bounds__(256) void softmax_kernel(
    const float* __restrict__ logits, const float* __restrict__ embedding,
    float* __restrict__ probs, float* __restrict__ preds,
    float* __restrict__ xcat, int t)
{
    const int b = blockIdx.x;
    const int tid = threadIdx.x;
    const float* row = logits + (size_t)b * VOCAB;
    __shared__ float sv[256];
    __shared__ int   si[256];

    // pass 1: max + first-index argmax
    float m = -INFINITY; int mi = 0;
    for (int v = tid; v < VOCAB; v += 256) {
        float x = row[v];
        if (x > m) { m = x; mi = v; }   // strict > keeps earliest in-thread
    }
    sv[tid] = m; si[tid] = mi;
    __syncthreads();
    for (int stp = 128; stp > 0; stp >>= 1) {
        if (tid < stp) {
            float vo = sv[tid + stp]; int io = si[tid + stp];
            if (vo > sv[tid] || (vo == sv[tid] && io < si[tid])) {
                sv[tid] = vo; si[tid] = io;
            }
        }
        __syncthreads();
    }
    const float gmax = sv[0];
    const int   gidx = si[0];
    __syncthreads();   // before reusing sv

    // pass 2: sum of exp (deterministic tree order)
    float sum = 0.0f;
    for (int v = tid; v < VOCAB; v += 256) sum += expf(row[v] - gmax);
    sv[tid] = sum;
    __syncthreads();
    for (int stp = 128; stp > 0; stp >>= 1) {
        if (tid < stp) sv[tid] += sv[tid + stp];
        __syncthreads();
    }
    const float inv = 1.0f / sv[0];

    // pass 3: write probabilities  (layout: probs[b][t][v])
    float* orow = probs + ((size_t)b * TSTEPS + t) * VOCAB;
    for (int v = tid; v < VOCAB; v += 256) orow[v] = expf(row[v] - gmax) * inv;

    if (tid == 0) preds[(size_t)b * TSTEPS + t] = (float)gidx;

    // gather next step's embedding row into xcat[:, 0:EDIM]
    const float* erow = embedding + (size_t)gidx * EDIM;
    float* xrow = xcat + (size_t)b * KCAT;
    for (int v = tid; v < EDIM; v += 256) xrow[v] = erow[v];
}

// ---------------------------------------------------------------------------
extern "C" void kernel_launch(void* const* d_in, const int* in_sizes, int n_in,
                              void* d_out, int out_size, void* d_ws, size_t ws_size,
                              hipStream_t stream)
{
    const float* hidden    = (const float*)d_in[0];
    const float* embedding = (const float*)d_in[1];
    const float* W_ih      = (const float*)d_in[2];
    const float* W_hh      = (const float*)d_in[3];
    const float* b_ih      = (const float*)d_in[4];
    const float* b_hh      = (const float*)d_in[5];
    const float* W_out     = (const float*)d_in[6];
    const float* b_out     = (const float*)d_in[7];

    float* probs = (float*)d_out;                               // B*T*V fp32
    float* preds = probs + (size_t)BATCH * TSTEPS * VOCAB;      // B*T as fp32

    // workspace layout (floats):
    float* ws     = (float*)d_ws;
    float* xcat   = ws;                                   // 64*2048
    float* cbuf   = xcat + (size_t)BATCH * KCAT;          // 64*1024
    float* gpart  = cbuf + (size_t)BATCH * HDIM;          // 8 * 64*4096
    float* logits = gpart + (size_t)8 * BATCH * G4;       // 64*32000
    // total ~4.34M floats = ~16.6 MB

    init_kernel<<<(BATCH * KCAT) / 256, 256, 0, stream>>>(hidden, embedding, xcat, cbuf);

    for (int t = 0; t < TSTEPS; ++t) {
        // gates: N=4096, K=2048 split into 8 slices (fills 256 CUs),
        // W = [W_ih | W_hh] along k with boundary at ldw=1024
        gemm_xwt<<<8 * 32, 256, 0, stream>>>(
            xcat, KCAT, W_ih, W_hh, HDIM,
            nullptr, gpart, (size_t)BATCH * G4,
            G4, KCAT, 8, 32);

        cell_kernel<<<(BATCH * HDIM) / 256, 256, 0, stream>>>(
            gpart, b_ih, b_hh, cbuf, xcat);

        // logits: X = h slice of xcat (ldx=2048), N=32000, K=1024
        gemm_xwt<<<VOCAB / 128, 256, 0, stream>>>(
            xcat + EDIM, KCAT, W_out, W_out, HDIM,
            b_out, logits, 0,
            VOCAB, HDIM, 1, VOCAB / 128);

        softmax_kernel<<<BATCH, 256, 0, stream>>>(
            logits, embedding, probs, preds, xcat, t);
    }
}

// Round 2
// 5292.184 us; speedup vs baseline: 2.0855x; 1.8635x over previous
//
#include <hip/hip_runtime.h>
#include <math.h>

#define BATCH 64
#define HDIM 1024
#define EDIM 1024
#define VOCAB 32000
#define TSTEPS 50
#define G4 4096      // 4*H
#define KCAT 2048    // EDIM + HDIM
#define STARTIDX 1
#define NSLICE_G 16  // split-K slices for gates GEMM (Ks=128)
#define NSLICE_L 2   // split-K slices for logits GEMM (Ks=512)

// ---------------------------------------------------------------------------
// init: xcat[b] = [ embedding[START_INDEX] | hidden[b] ],  c = 0
// ---------------------------------------------------------------------------
__global__ __launch_bounds__(256) void init_kernel(
    const float* __restrict__ hidden, const float* __restrict__ embedding,
    float* __restrict__ xcat, float* __restrict__ c)
{
    int tid = blockIdx.x * 256 + threadIdx.x;   // 0 .. 64*2048-1
    int b = tid >> 11;
    int j = tid & 2047;
    if (j < EDIM) {
        xcat[(size_t)b * KCAT + j] = embedding[(size_t)STARTIDX * EDIM + j];
    } else {
        int k = j - EDIM;
        xcat[(size_t)b * KCAT + j] = hidden[(size_t)b * HDIM + k];
        c[(size_t)b * HDIM + k] = 0.0f;
    }
}

// ---------------------------------------------------------------------------
// C_slice[s] (64 x N-coltile) = X[:, kbase:kbase+Ks] @ Wsel^T
// Block: 128 threads (2 waves), tile 64 rows x 128 cols, 8x8 micro-tile.
// LDS balance: 64 B LDS read per 64 FMAs/thread = 1.0 B/lane-FMA -> LDS
// (128 B/cyc/CU) and VALU (128 lane-FMA/cyc/CU) co-critical (was 1.5 with 4x8).
// Software-pipelined: register prefetch of tile k+1 before the FMA block,
// LDS double-buffered, ONE barrier per k-iteration.
// Split-K slices write separate partial buffers (deterministic, no atomics);
// ~2 blocks/CU so one block's barrier overlaps the other block's compute.
// ---------------------------------------------------------------------------
__global__ __launch_bounds__(128) void gemm8x8(
    const float* __restrict__ X, int ldx,
    const float* __restrict__ W0, const float* __restrict__ W1, int ldw,
    float* __restrict__ C, size_t c_slice_stride,
    int N, int Ktotal, int nslices, int coltiles)
{
    __shared__ float Xs[2][16][68];    // [buf][kk][row]
    __shared__ float Ws[2][16][132];   // [buf][kk][col]

    const int tid = threadIdx.x;
    const int bx  = blockIdx.x;
    const int s   = bx / coltiles;
    const int ct  = bx - s * coltiles;
    const int Ks  = Ktotal / nslices;
    const int kbase = s * Ks;
    const float* Xp = X + kbase;
    const float* Wp = (kbase < ldw) ? (W0 + kbase) : (W1 + (kbase - ldw));
    const int colBase = ct * 128;

    const int trow8 = (tid >> 4) * 8;     // 0..56 (8 thread-rows)
    const int tcol8 = (tid & 15) * 8;     // 0..120 (16 thread-cols)
    const int xr = tid & 63;              // staging: X row
    const int xh = (tid >> 6) * 8;        // staging: X k-half (0 or 8)

    const float* xg = Xp + (size_t)xr * ldx + xh;
    const float* wg = Wp + (size_t)(colBase + tid) * ldw;

    float acc[8][8];
#pragma unroll
    for (int i = 0; i < 8; ++i)
#pragma unroll
        for (int j = 0; j < 8; ++j) acc[i][j] = 0.0f;

    // ---- prologue: stage tile 0 into buffer 0 ----
    {
        float4 xa = *(const float4*)(xg);
        float4 xb = *(const float4*)(xg + 4);
        float4 w0 = *(const float4*)(wg);
        float4 w1 = *(const float4*)(wg + 4);
        float4 w2 = *(const float4*)(wg + 8);
        float4 w3 = *(const float4*)(wg + 12);
        Xs[0][xh+0][xr] = xa.x; Xs[0][xh+1][xr] = xa.y;
        Xs[0][xh+2][xr] = xa.z; Xs[0][xh+3][xr] = xa.w;
        Xs[0][xh+4][xr] = xb.x; Xs[0][xh+5][xr] = xb.y;
        Xs[0][xh+6][xr] = xb.z; Xs[0][xh+7][xr] = xb.w;
        Ws[0][ 0][tid] = w0.x; Ws[0][ 1][tid] = w0.y;
        Ws[0][ 2][tid] = w0.z; Ws[0][ 3][tid] = w0.w;
        Ws[0][ 4][tid] = w1.x; Ws[0][ 5][tid] = w1.y;
        Ws[0][ 6][tid] = w1.z; Ws[0][ 7][tid] = w1.w;
        Ws[0][ 8][tid] = w2.x; Ws[0][ 9][tid] = w2.y;
        Ws[0][10][tid] = w2.z; Ws[0][11][tid] = w2.w;
        Ws[0][12][tid] = w3.x; Ws[0][13][tid] = w3.y;
        Ws[0][14][tid] = w3.z; Ws[0][15][tid] = w3.w;
    }
    __syncthreads();

    const int niter = Ks >> 4;
    int cur = 0;
#pragma unroll 2
    for (int it = 1; it < niter; ++it) {
        const int k0 = it << 4;
        // prefetch next tile into registers (vmcnt wait lands after ~2048cy
        // of FMA issue -> global latency hidden)
        float4 xa = *(const float4*)(xg + k0);
        float4 xb = *(const float4*)(xg + k0 + 4);
        float4 w0 = *(const float4*)(wg + k0);
        float4 w1 = *(const float4*)(wg + k0 + 4);
        float4 w2 = *(const float4*)(wg + k0 + 8);
        float4 w3 = *(const float4*)(wg + k0 + 12);

        // compute on current buffer
        {
            const float (*Xc)[68]  = Xs[cur];
            const float (*Wc)[132] = Ws[cur];
#pragma unroll
            for (int kk = 0; kk < 16; ++kk) {
                float4 a0 = *(const float4*)&Xc[kk][trow8];
                float4 a1 = *(const float4*)&Xc[kk][trow8 + 4];
                float4 b0 = *(const float4*)&Wc[kk][tcol8];
                float4 b1 = *(const float4*)&Wc[kk][tcol8 + 4];
                float a[8]  = {a0.x,a0.y,a0.z,a0.w,a1.x,a1.y,a1.z,a1.w};
                float bb[8] = {b0.x,b0.y,b0.z,b0.w,b1.x,b1.y,b1.z,b1.w};
#pragma unroll
                for (int i = 0; i < 8; ++i)
#pragma unroll
                    for (int j = 0; j < 8; ++j)
                        acc[i][j] += a[i] * bb[j];
            }
        }

        // stage prefetched tile into the other buffer (safe with a single
        // barrier: buffer nb was last READ before the previous barrier).
        const int nb = cur ^ 1;
        Xs[nb][xh+0][xr] = xa.x; Xs[nb][xh+1][xr] = xa.y;
        Xs[nb][xh+2][xr] = xa.z; Xs[nb][xh+3][xr] = xa.w;
        Xs[nb][xh+4][xr] = xb.x; Xs[nb][xh+5][xr] = xb.y;
        Xs[nb][xh+6][xr] = xb.z; Xs[nb][xh+7][xr] = xb.w;
        Ws[nb][ 0][tid] = w0.x; Ws[nb][ 1][tid] = w0.y;
        Ws[nb][ 2][tid] = w0.z; Ws[nb][ 3][tid] = w0.w;
        Ws[nb][ 4][tid] = w1.x; Ws[nb][ 5][tid] = w1.y;
        Ws[nb][ 6][tid] = w1.z; Ws[nb][ 7][tid] = w1.w;
        Ws[nb][ 8][tid] = w2.x; Ws[nb][ 9][tid] = w2.y;
        Ws[nb][10][tid] = w2.z; Ws[nb][11][tid] = w2.w;
        Ws[nb][12][tid] = w3.x; Ws[nb][13][tid] = w3.y;
        Ws[nb][14][tid] = w3.z; Ws[nb][15][tid] = w3.w;
        __syncthreads();
        cur = nb;
    }

    // ---- epilogue compute on the last staged tile ----
    {
        const float (*Xc)[68]  = Xs[cur];
        const float (*Wc)[132] = Ws[cur];
#pragma unroll
        for (int kk = 0; kk < 16; ++kk) {
            float4 a0 = *(const float4*)&Xc[kk][trow8];
            float4 a1 = *(const float4*)&Xc[kk][trow8 + 4];
            float4 b0 = *(const float4*)&Wc[kk][tcol8];
            float4 b1 = *(const float4*)&Wc[kk][tcol8 + 4];
            float a[8]  = {a0.x,a0.y,a0.z,a0.w,a1.x,a1.y,a1.z,a1.w};
            float bb[8] = {b0.x,b0.y,b0.z,b0.w,b1.x,b1.y,b1.z,b1.w};
#pragma unroll
            for (int i = 0; i < 8; ++i)
#pragma unroll
                for (int j = 0; j < 8; ++j)
                    acc[i][j] += a[i] * bb[j];
        }
    }

    float* Cs = C + (size_t)s * c_slice_stride + (size_t)colBase + tcol8;
#pragma unroll
    for (int i = 0; i < 8; ++i) {
        float* crow = Cs + (size_t)(trow8 + i) * N;
        float4 c0 = {acc[i][0], acc[i][1], acc[i][2], acc[i][3]};
        float4 c1 = {acc[i][4], acc[i][5], acc[i][6], acc[i][7]};
        *(float4*)(crow)     = c0;
        *(float4*)(crow + 4) = c1;
    }
}

// ---------------------------------------------------------------------------
// cell: gate[b][j] = sum_s gpart[s][b][j] + b_ih[j] + b_hh[j]  (fixed order ->
// deterministic), then LSTM update; h_new written into xcat[:,EDIM:].
// ---------------------------------------------------------------------------
__global__ __launch_bounds__(256) void cell_kernel(
    const float* __restrict__ gpart,   // [NSLICE_G][64*4096]
    const float* __restrict__ b_ih, const float* __restrict__ b_hh,
    float* __restrict__ c, float* __restrict__ xcat)
{
    int tid = blockIdx.x * 256 + threadIdx.x;   // 0..65535
    int b = tid >> 10;
    int k = tid & 1023;
    size_t base = (size_t)b * G4;
    float g[4];
#pragma unroll
    for (int q = 0; q < 4; ++q) {
        int j = k + q * HDIM;
        float v = b_ih[j] + b_hh[j];
#pragma unroll
        for (int sN = 0; sN < NSLICE_G; ++sN)
            v += gpart[(size_t)sN * ((size_t)BATCH * G4) + base + j];
        g[q] = v;
    }
    float sig_i = 1.0f / (1.0f + expf(-g[0]));
    float sig_f = 1.0f / (1.0f + expf(-g[1]));
    float sig_o = 1.0f / (1.0f + expf(-g[3]));
    float cn = sig_f * c[tid] + sig_i * tanhf(g[2]);
    float hn = sig_o * tanhf(cn);
    c[tid] = cn;
    xcat[(size_t)b * KCAT + EDIM + k] = hn;
}

// ---------------------------------------------------------------------------
// softmax over partial logits: logits[v] = lp0[v] + lp1[v] + b_out[v].
// One block of 1024 threads per batch row; the whole row is read ONCE into
// registers (8 x float4 per thread), then max/argmax, sum, and the prob write
// all run from registers. Reductions: wave shuffle-butterfly -> 16-entry LDS
// -> serial scan by thread 0 (deterministic; lexicographic (val, idx)
// comparator preserves np.argmax first-index tie-break).
// ---------------------------------------------------------------------------
__global__ __launch_bounds__(1024) void softmax_kernel(
    const float* __restrict__ lp,      // [NSLICE_L][BATCH][VOCAB]
    const float* __restrict__ b_out,
    const float* __restrict__ embedding,
    float* __restrict__ probs, float* __restrict__ preds,
    float* __restrict__ xcat, int t)
{
    const int b = blockIdx.x;
    const int tid  = threadIdx.x;
    const int lane = tid & 63;
    const int wid  = tid >> 6;         // 0..15
    const float4* p0 = (const float4*)(lp + (size_t)b * VOCAB);
    const float4* p1 = (const float4*)(lp + (size_t)BATCH * VOCAB + (size_t)b * VOCAB);
    const float4* bo = (const float4*)b_out;

    __shared__ float swv[16];
    __shared__ int   swi[16];

    // pass 1: load + combine + in-thread max/argmax (ascending index order)
    float4 rv[8];
    float m = -INFINITY; int mi = 0;
#pragma unroll
    for (int p = 0; p < 8; ++p) {
        int q = tid + (p << 10);                   // float4 index
        if (q < VOCAB / 4) {
            float4 a = p0[q], c = p1[q], bb = bo[q];
            float4 v;
            v.x = a.x + c.x + bb.x;
            v.y = a.y + c.y + bb.y;
            v.z = a.z + c.z + bb.z;
            v.w = a.w + c.w + bb.w;
            rv[p] = v;
            int vb = q << 2;
            if (v.x > m) { m = v.x; mi = vb;     }
            if (v.y > m) { m = v.y; mi = vb + 1; }
            if (v.z > m) { m = v.z; mi = vb + 2; }
            if (v.w > m) { m = v.w; mi = vb + 3; }
        }
    }
    // wave butterfly (symmetric lexicographic comparator -> deterministic)
#pragma unroll
    for (int off = 32; off > 0; off >>= 1) {
        float om = __shfl_xor(m, off, 64);
        int   oi = __shfl_xor(mi, off, 64);
        if (om > m || (om == m && oi < mi)) { m = om; mi = oi; }
    }
    if (lane == 0) { swv[wid] = m; swi[wid] = mi; }
    __syncthreads();
    if (tid == 0) {
        float gm = swv[0]; int gi = swi[0];
        for (int w = 1; w < 16; ++w) {
            if (swv[w] > gm || (swv[w] == gm && swi[w] < gi)) { gm = swv[w]; gi = swi[w]; }
        }
        swv[0] = gm; swi[0] = gi;
    }
    __syncthreads();
    const float gmax = swv[0];
    const int   gidx = swi[0];
    __syncthreads();   // everyone has gmax/gidx before swv is reused

    // pass 2: sum of exp (from registers)
    float sum = 0.0f;
#pragma unroll
    for (int p = 0; p < 8; ++p) {
        int q = tid + (p << 10);
        if (q < VOCAB / 4) {
            float4 v = rv[p];
            sum += expf(v.x - gmax) + expf(v.y - gmax)
                 + expf(v.z - gmax) + expf(v.w - gmax);
        }
    }
#pragma unroll
    for (int off = 32; off > 0; off >>= 1)
        sum += __shfl_xor(sum, off, 64);
    if (lane == 0) swv[wid] = sum;
    __syncthreads();
    if (tid == 0) {
        float s = swv[0];
        for (int w = 1; w < 16; ++w) s += swv[w];
        swv[0] = 1.0f / s;
    }
    __syncthreads();
    const float inv = swv[0];

    // pass 3: write probabilities from registers (layout: probs[b][t][v])
    float4* orow = (float4*)(probs + ((size_t)b * TSTEPS + t) * VOCAB);
#pragma unroll
    for (int p = 0; p < 8; ++p) {
        int q = tid + (p << 10);
        if (q < VOCAB / 4) {
            float4 v = rv[p], o;
            o.x = expf(v.x - gmax) * inv;
            o.y = expf(v.y - gmax) * inv;
            o.z = expf(v.z - gmax) * inv;
            o.w = expf(v.w - gmax) * inv;
            orow[q] = o;
        }
    }

    if (tid == 0) preds[(size_t)b * TSTEPS + t] = (float)gidx;

    // gather next step's embedding row into xcat[:, 0:EDIM]
    if (tid < EDIM / 4) {
        const float4* er = (const float4*)(embedding + (size_t)gidx * EDIM);
        float4* xr = (float4*)(xcat + (size_t)b * KCAT);
        xr[tid] = er[tid];
    }
}

// ---------------------------------------------------------------------------
extern "C" void kernel_launch(void* const* d_in, const int* in_sizes, int n_in,
                              void* d_out, int out_size, void* d_ws, size_t ws_size,
                              hipStream_t stream)
{
    const float* hidden    = (const float*)d_in[0];
    const float* embedding = (const float*)d_in[1];
    const float* W_ih      = (const float*)d_in[2];
    const float* W_hh      = (const float*)d_in[3];
    const float* b_ih      = (const float*)d_in[4];
    const float* b_hh      = (const float*)d_in[5];
    const float* W_out     = (const float*)d_in[6];
    const float* b_out     = (const float*)d_in[7];

    float* probs = (float*)d_out;                               // B*T*V fp32
    float* preds = probs + (size_t)BATCH * TSTEPS * VOCAB;      // B*T as fp32

    // workspace layout (floats):
    float* ws    = (float*)d_ws;
    float* xcat  = ws;                                    // 64*2048
    float* cbuf  = xcat + (size_t)BATCH * KCAT;           // 64*1024
    float* spart = cbuf + (size_t)BATCH * HDIM;           // union buffer:
    float* gpart = spart;   // [16][64*4096] gate partials   (live gemm->cell)
    float* lpart = spart;   // [ 2][64*32000] logit partials (live gemm->softmax)
    // union size = max(16*64*4096, 2*64*32000) = 4.19M floats; total ~17 MB

    init_kernel<<<(BATCH * KCAT) / 256, 256, 0, stream>>>(hidden, embedding, xcat, cbuf);

    for (int t = 0; t < TSTEPS; ++t) {
        // gates: N=4096, K=2048 in 16 slices (512 blocks -> ~2/CU),
        // W = [W_ih | W_hh] along k with boundary at ldw=1024
        gemm8x8<<<NSLICE_G * 32, 128, 0, stream>>>(
            xcat, KCAT, W_ih, W_hh, HDIM,
            gpart, (size_t)BATCH * G4,
            G4, KCAT, NSLICE_G, 32);

        cell_kernel<<<(BATCH * HDIM) / 256, 256, 0, stream>>>(
            gpart, b_ih, b_hh, cbuf, xcat);

        // logits: X = h slice of xcat (ldx=2048), N=32000, K=1024 in 2 slices
        // (500 blocks -> ~2/CU); b_out folded into softmax
        gemm8x8<<<NSLICE_L * 250, 128, 0, stream>>>(
            xcat + EDIM, KCAT, W_out, W_out, HDIM,
            lpart, (size_t)BATCH * VOCAB,
            VOCAB, HDIM, NSLICE_L, 250);

        softmax_kernel<<<BATCH, 1024, 0, stream>>>(
            lpart, b_out, embedding, probs, preds, xcat, t);
    }
}